// Round 2
// baseline (161.682 us; speedup 1.0000x reference)
//
#include <hip/hip_runtime.h>

// out[token, h] = W[h, ids[token]] + b[h]
// W: [HIDDEN, VOCAB] row-major f32; out: [tokens, HIDDEN] f32.
//
// Gather formulation of the one-hot matmul (one-hot selects a single W
// column). Latency-bound kernel -> maximize independent loads in flight:
// 4 tokens per 256-thread block, each thread issues 16 independent
// strided gathers (vs 4 in the previous round) before any use.

#define VOCAB 32000
#define HIDDEN 1024
#define TPB 4  // tokens per block

__global__ __launch_bounds__(256) void onehot_gather_kernel(
    const int* __restrict__ ids,
    const float* __restrict__ W,
    const float* __restrict__ b,
    float* __restrict__ out,
    int n_tokens)
{
    const int t    = threadIdx.x;
    const int sub  = t >> 6;      // token slot within block (0..3)
    const int lane = t & 63;
    const int token = blockIdx.x * TPB + sub;
    if (token >= n_tokens) return;

    const int id = ids[token];                 // wave-uniform -> scalar load
    const float* Wcol = W + (size_t)id;        // column base

    // Phase 1: issue all 16 gathers into registers (static indexing only).
    float v[16];
    #pragma unroll
    for (int j = 0; j < 4; ++j) {
        const int h0 = j * 256 + lane * 4;     // 64 lanes x 4 h, 4 j-chunks
        #pragma unroll
        for (int k = 0; k < 4; ++k)
            v[j * 4 + k] = Wcol[(size_t)(h0 + k) * VOCAB];
    }

    // Phase 2: bias + coalesced float4 stores.
    float* orow = out + (size_t)token * HIDDEN;
    #pragma unroll
    for (int j = 0; j < 4; ++j) {
        const int h0 = j * 256 + lane * 4;
        const float4 bv = *reinterpret_cast<const float4*>(&b[h0]);
        float4 o;
        o.x = v[j * 4 + 0] + bv.x;
        o.y = v[j * 4 + 1] + bv.y;
        o.z = v[j * 4 + 2] + bv.z;
        o.w = v[j * 4 + 3] + bv.w;
        *reinterpret_cast<float4*>(&orow[h0]) = o;
    }
}

extern "C" void kernel_launch(void* const* d_in, const int* in_sizes, int n_in,
                              void* d_out, int out_size, void* d_ws, size_t ws_size,
                              hipStream_t stream)
{
    const int*   ids = (const int*)d_in[0];    // [BATCH*SEQ] int32
    const float* W   = (const float*)d_in[1];  // [HIDDEN, VOCAB] f32
    const float* b   = (const float*)d_in[2];  // [HIDDEN] f32
    float*       out = (float*)d_out;          // [BATCH*SEQ, HIDDEN] f32

    const int n_tokens = in_sizes[0];          // 8192
    const int nblocks  = (n_tokens + TPB - 1) / TPB;

    onehot_gather_kernel<<<dim3(nblocks), dim3(256), 0, stream>>>(
        ids, W, b, out, n_tokens);
}

// Round 3
// 62.605 us; speedup vs baseline: 2.5826x; 2.5826x over previous
//
#include <hip/hip_runtime.h>

// out[token, h] = W[h, ids[token]] + b[h]   (one-hot matmul == column gather)
// W: [HIDDEN, VOCAB] row-major f32.
//
// Round-2 counters: FETCH_SIZE 504 MB vs 131 MB distinct-line floor ->
// per-line reuse (avg ~4 tokens share a 64B W-line) not captured.
// Fix: process tokens in id-sorted order (counting sort by line-bin id>>4),
// so same-line tokens are adjacent in the grid -> L1/L2 hits. XCD-chunked
// block swizzle keeps id-adjacent blocks on the same L2.

#define VOCAB  32000
#define HIDDEN 1024
#define TPB    4      // tokens per block in the gather kernel
#define NBINS  2048   // bins of 16 ids (one 64B line per h-row); 32000/16=2000<2048

__global__ __launch_bounds__(256) void hist_kernel(
    const int* __restrict__ ids, int n, int* __restrict__ bin_count)
{
    int i = blockIdx.x * blockDim.x + threadIdx.x;
    if (i < n) atomicAdd(&bin_count[ids[i] >> 4], 1);
}

// Single-block Blelloch exclusive scan over NBINS=2048 (1024 threads).
__global__ __launch_bounds__(1024) void scan_kernel(
    const int* __restrict__ bin_count, int* __restrict__ bin_pos)
{
    __shared__ int tmp[NBINS];
    const int t = threadIdx.x;
    tmp[2 * t]     = bin_count[2 * t];
    tmp[2 * t + 1] = bin_count[2 * t + 1];

    int offset = 1;
    for (int d = NBINS >> 1; d > 0; d >>= 1) {
        __syncthreads();
        if (t < d) {
            int ai = offset * (2 * t + 1) - 1;
            int bi = offset * (2 * t + 2) - 1;
            tmp[bi] += tmp[ai];
        }
        offset <<= 1;
    }
    __syncthreads();
    if (t == 0) tmp[NBINS - 1] = 0;
    for (int d = 1; d < NBINS; d <<= 1) {
        offset >>= 1;
        __syncthreads();
        if (t < d) {
            int ai = offset * (2 * t + 1) - 1;
            int bi = offset * (2 * t + 2) - 1;
            int x = tmp[ai];
            tmp[ai] = tmp[bi];
            tmp[bi] += x;
        }
    }
    __syncthreads();
    bin_pos[2 * t]     = tmp[2 * t];
    bin_pos[2 * t + 1] = tmp[2 * t + 1];
}

__global__ __launch_bounds__(256) void scatter_kernel(
    const int* __restrict__ ids, int n, int* __restrict__ bin_pos,
    int* __restrict__ perm)
{
    int i = blockIdx.x * blockDim.x + threadIdx.x;
    if (i < n) {
        int p = atomicAdd(&bin_pos[ids[i] >> 4], 1);
        perm[p] = i;
    }
}

__global__ __launch_bounds__(256) void onehot_gather_kernel(
    const int* __restrict__ ids,
    const int* __restrict__ perm,   // may be nullptr (unsorted fallback)
    const float* __restrict__ W,
    const float* __restrict__ b,
    float* __restrict__ out,
    int n_tokens)
{
    // XCD-chunked swizzle: 8 XCDs each get a contiguous (id-sorted) range.
    int bid = blockIdx.x;
    const int nwg = gridDim.x;
    if ((nwg & 7) == 0) bid = (bid & 7) * (nwg >> 3) + (bid >> 3);

    const int t    = threadIdx.x;
    const int sub  = t >> 6;       // token slot within block (0..3)
    const int lane = t & 63;
    const int gidx = bid * TPB + sub;
    if (gidx >= n_tokens) return;

    const int token = perm ? perm[gidx] : gidx;   // original token index
    const int id = ids[token];
    const float* Wcol = W + (size_t)id;

    // Phase 1: issue 16 independent gathers (static indexing only).
    float v[16];
    #pragma unroll
    for (int j = 0; j < 4; ++j) {
        const int h0 = j * 256 + lane * 4;
        #pragma unroll
        for (int k = 0; k < 4; ++k)
            v[j * 4 + k] = Wcol[(size_t)(h0 + k) * VOCAB];
    }

    // Phase 2: bias + coalesced float4 stores to the ORIGINAL row.
    float* orow = out + (size_t)token * HIDDEN;
    #pragma unroll
    for (int j = 0; j < 4; ++j) {
        const int h0 = j * 256 + lane * 4;
        const float4 bv = *reinterpret_cast<const float4*>(&b[h0]);
        float4 o;
        o.x = v[j * 4 + 0] + bv.x;
        o.y = v[j * 4 + 1] + bv.y;
        o.z = v[j * 4 + 2] + bv.z;
        o.w = v[j * 4 + 3] + bv.w;
        *reinterpret_cast<float4*>(&orow[h0]) = o;
    }
}

extern "C" void kernel_launch(void* const* d_in, const int* in_sizes, int n_in,
                              void* d_out, int out_size, void* d_ws, size_t ws_size,
                              hipStream_t stream)
{
    const int*   ids = (const int*)d_in[0];    // [BATCH*SEQ] int32
    const float* W   = (const float*)d_in[1];  // [HIDDEN, VOCAB] f32
    const float* b   = (const float*)d_in[2];  // [HIDDEN] f32
    float*       out = (float*)d_out;          // [BATCH*SEQ, HIDDEN] f32

    const int n_tokens = in_sizes[0];          // 8192
    const int nblocks  = (n_tokens + TPB - 1) / TPB;

    // Workspace layout: bin_count[NBINS] | bin_pos[NBINS] | perm[n_tokens]
    const size_t need = (size_t)(2 * NBINS + n_tokens) * sizeof(int);
    int* perm = nullptr;

    if (ws_size >= need) {
        int* bin_count = (int*)d_ws;
        int* bin_pos   = bin_count + NBINS;
        perm           = bin_pos + NBINS;

        hipMemsetAsync(bin_count, 0, NBINS * sizeof(int), stream);
        hist_kernel<<<dim3((n_tokens + 255) / 256), dim3(256), 0, stream>>>(
            ids, n_tokens, bin_count);
        scan_kernel<<<dim3(1), dim3(1024), 0, stream>>>(bin_count, bin_pos);
        scatter_kernel<<<dim3((n_tokens + 255) / 256), dim3(256), 0, stream>>>(
            ids, n_tokens, bin_pos, perm);
    }

    onehot_gather_kernel<<<dim3(nblocks), dim3(256), 0, stream>>>(
        ids, perm, W, b, out, n_tokens);
}